// Round 10
// baseline (61.419 us; speedup 1.0000x reference)
//
#include <hip/hip_runtime.h>

#define CCH  85
#define N0   (16*13*13*3)   // 8112
#define N1   (16*26*26*3)   // 32448
#define N2   (16*52*52*3)   // 129792
#define NTOT (N0+N1+N2)     // 170352
#define NBLK ((NTOT + 255) / 256)   // 666
#define MAXB 32
#define LOBJ 48   // max own obj cells per block (<=2 images x <=20)

// d_ws layout (bytes) -- [0,512) zeroed by the memset node each call:
//   [0,192)    counts[48]
//   [192,384)  done[48]     per-span ticket
//   [384,388)  done2        block-completion ticket
//   [388,392)  accum        float loss accumulator
//   [512,25088) boxes[48][MAXB][4] floats (atomic-published)
#define DONE_OFF  192
#define DONE2_OFF 384
#define ACC_OFF   388
#define BOX_OFF   512

typedef float v4f __attribute__((ext_vector_type(4), aligned(4)));

__device__ __forceinline__ void decode(int i, int& l, int& li, int& g) {
    if (i < N0)           { l = 0; li = i;           g = 13; }
    else if (i < N0 + N1) { l = 1; li = i - N0;      g = 26; }
    else                  { l = 2; li = i - N0 - N1; g = 52; }
}

// anchors fixed by reference setup_inputs; l0->mask[6,7,8], l1->[3,4,5], l2->[0,1,2]
__device__ __forceinline__ float anc_x(int l, int a) {
    if (l == 0) return (a == 0) ? 116.f : (a == 1) ? 156.f : 373.f;
    if (l == 1) return (a == 0) ?  30.f : (a == 1) ?  62.f :  59.f;
    return          (a == 0) ?  10.f : (a == 1) ?  16.f :  33.f;
}
__device__ __forceinline__ float anc_y(int l, int a) {
    if (l == 0) return (a == 0) ?  90.f : (a == 1) ? 198.f : 326.f;
    if (l == 1) return (a == 0) ?  61.f : (a == 1) ?  45.f : 119.f;
    return          (a == 0) ?  13.f : (a == 1) ?  30.f :  23.f;
}

__device__ __forceinline__ int lb_of(int gi) {
    int ll, lli, gg;
    decode(gi, ll, lli, gg);
    return ll * 16 + lli / (gg * gg * 3);
}

// number of 256-thread blocks whose cell range intersects span lb
__device__ __forceinline__ int span_nblk(int lb) {
    int l = lb >> 4, b = lb & 15;
    int st, cpi;
    if (l == 0)      { st = 0;       cpi = 13 * 13 * 3; }
    else if (l == 1) { st = N0;      cpi = 26 * 26 * 3; }
    else             { st = N0 + N1; cpi = 52 * 52 * 3; }
    int s = st + b * cpi, e = s + cpi;
    return ((e - 1) >> 8) - (s >> 8) + 1;
}

// ---------------------------------------------------------------------------
// ONE fused kernel, per-span tickets (NOT a global barrier):
//  - each block publishes its own obj boxes via device-scope atomicExch, then
//    (after __syncthreads' vmcnt drain = release point) bumps done[span].
//  - a block waits ONLY for its own <=2 spans' sibling blocks (leader-only
//    s_sleep spin on done[lb]); boxes/counts are then read back with atomic
//    reads (atomicAdd(p,0)) -> no consumer fence, no L2 invalidate.
//  - obj-cell full loss runs between publish and spin (overlap).
//  - output: block partials atomicAdd into ws accum; last block (done2)
//    plain-stores out[0]. No d_out memset node needed.
// Residency: 666 blocks x 4 waves, 36ish VGPR, ~1.6KB LDS -> all co-resident.
// Ref's top_k(32)+(vals>0) mask == set of obj>0 boxes (<=20/image < 32);
// set-max IoU is order-independent -> append order irrelevant.
// ---------------------------------------------------------------------------
__global__ void __launch_bounds__(256) yolo_fused(
        const float* __restrict__ p0, const float* __restrict__ t0,
        const float* __restrict__ p1, const float* __restrict__ t1,
        const float* __restrict__ p2, const float* __restrict__ t2,
        int* __restrict__ counts, int* __restrict__ done,
        int* __restrict__ done2, float* __restrict__ accum,
        float* __restrict__ boxes, float* __restrict__ out) {
    int bid = blockIdx.x;
    int tid = threadIdx.x;
    int i = bid * 256 + tid;
    bool valid = i < NTOT;

    int l = 0, li = 0, g = 13;
    if (valid) decode(i, l, li, g);
    const float* P = (l == 0) ? p0 : (l == 1) ? p1 : p2;
    const float* T = (l == 0) ? t0 : (l == 1) ? t1 : t2;
    size_t base = (size_t)li * CCH;

    // own-cell gathers first (one latency shadow for pred + tgt-obj)
    v4f pv4 = {0.5f, 0.5f, 0.0f, 0.0f};
    float pc = 0.5f, obj = 0.0f;
    if (valid) {
        pv4 = *(const v4f*)(P + base);
        pc  = P[base + 4];
        obj = T[base + 4];
    }

    int cpi = g * g * 3;
    int b = li / cpi;
    int c = li % cpi;
    int a = c % 3;
    int w = (c / 3) % g;
    int h = c / (3 * g);
    int lb = l * 16 + b;

    int iLast = (bid * 256 + 255 < NTOT) ? bid * 256 + 255 : NTOT - 1;
    int lbA = lb_of(bid * 256);
    int lbB = lb_of(iLast);

    __shared__ int lcnt;
    __shared__ int lcell[LOBJ];
    if (tid == 0) lcnt = 0;
    __syncthreads();

    // publish own obj boxes (device-scope atomics = coherent point)
    if (valid && obj > 0.0f) {
        v4f tb4 = *(const v4f*)(T + base);
        int pos = atomicAdd(&counts[lb], 1);
        if (pos < MAXB) {
            float* dst = boxes + ((size_t)lb * MAXB + pos) * 4;
            atomicExch(dst + 0, tb4.x);
            atomicExch(dst + 1, tb4.y);
            atomicExch(dst + 2, tb4.z);
            atomicExch(dst + 3, tb4.w);
        }
        int lp = atomicAdd(&lcnt, 1);
        if (lp < LOBJ) lcell[lp] = (l << 20) | li;
    }
    __syncthreads();   // vmcnt drain: all block publishes complete here

    // per-span tickets (this block's publishes are globally performed)
    if (tid == 0) atomicAdd(&done[lbA], 1);
    if (tid == 1 && lbB != lbA) atomicAdd(&done[lbB], 1);

    // obj-cell full loss (xy/wh/cls), wave-cooperative; overlaps siblings
    float acc = 0.0f;
    int lane = tid & 63, wid = tid >> 6;
    int n = lcnt < LOBJ ? lcnt : LOBJ;
    for (int k = wid; k < n; k += 4) {
        int enc = lcell[k];
        int l2 = enc >> 20, li2 = enc & 0xFFFFF;
        const float *P2, *T2; int g2;
        if (l2 == 0)      { g2 = 13; P2 = p0; T2 = t0; }
        else if (l2 == 1) { g2 = 26; P2 = p1; T2 = t1; }
        else              { g2 = 52; P2 = p2; T2 = t2; }
        int cpi2 = g2 * g2 * 3;
        int c2 = li2 % cpi2;
        int a2 = c2 % 3;
        int w2 = (c2 / 3) % g2;
        int h2 = c2 / (3 * g2);
        size_t base2 = (size_t)li2 * CCH;

        float pv = P2[base2 + lane];
        float tv = T2[base2 + lane];
        bool has2 = lane < (CCH - 64);
        float pvB = 1.0f, tvB = 1.0f;
        if (has2) { pvB = P2[base2 + 64 + lane]; tvB = T2[base2 + 64 + lane]; }

        float tx = __shfl(tv, 0, 64), ty = __shfl(tv, 1, 64);
        float tw = __shfl(tv, 2, 64), th = __shfl(tv, 3, 64);
        float qx = __shfl(pv, 0, 64), qy = __shfl(pv, 1, 64);
        float qw = __shfl(pv, 2, 64), qh = __shfl(pv, 3, 64);

        if (lane >= 5)
            acc += -(tv * __logf(pv) + (1.0f - tv) * __logf(1.0f - pv));
        if (has2)
            acc += -(tvB * __logf(pvB) + (1.0f - tvB) * __logf(1.0f - pvB));

        if (lane == 0) {
            float scale = 2.0f - tw * th;
            float gf = (float)g2;
            float rtx = tx * gf - (float)w2;
            float rty = ty * gf - (float)h2;
            float ax = anc_x(l2, a2), ay = anc_y(l2, a2);
            float rtw = __logf(tw * 416.0f / ax);
            float rth = __logf(th * 416.0f / ay);
            acc += (-(rtx * __logf(qx) + (1.0f - rtx) * __logf(1.0f - qx))) * scale;
            acc += (-(rty * __logf(qy) + (1.0f - rty) * __logf(1.0f - qy))) * scale;
            acc += 0.5f * (qw - rtw) * (qw - rtw) * scale;
            acc += 0.5f * (qh - rth) * (qh - rth) * scale;
        }
    }

    // leader-only spin, own spans only (short: sibling publish skew)
    int nblkA = span_nblk(lbA);
    int nblkB = span_nblk(lbB);
    if (tid == 0) {
        while (atomicAdd(&done[lbA], 0) < nblkA)
            __builtin_amdgcn_s_sleep(1);
    }
    if (tid == 1 && lbB != lbA) {
        while (atomicAdd(&done[lbB], 0) < nblkB)
            __builtin_amdgcn_s_sleep(1);
    }
    __syncthreads();

    // read counts/boxes via ATOMIC reads (coherence point; no fence needed)
    __shared__ int scnt[2];
    __shared__ float sbox[2][MAXB * 4];
    if (tid == 0) { int v = atomicAdd(&counts[lbA], 0); scnt[0] = v < MAXB ? v : MAXB; }
    if (tid == 1) {
        int v = (lbB != lbA) ? atomicAdd(&counts[lbB], 0) : 0;
        scnt[1] = v < MAXB ? v : MAXB;
    }
    if (tid < 128)
        sbox[0][tid] = atomicAdd(boxes + (size_t)lbA * MAXB * 4 + tid, 0.0f);
    else if (lbB != lbA)
        sbox[1][tid - 128] = atomicAdd(boxes + (size_t)lbB * MAXB * 4 + (tid - 128), 0.0f);
    __syncthreads();

    // conf loss per cell (pred in registers, boxes in LDS)
    if (valid) {
        if (obj > 0.0f) {
            acc += -__logf(pc);                       // (obj+(1-obj)*ignore)==1
        } else {
            float ax = anc_x(l, a), ay = anc_y(l, a);
            float gf = (float)g;
            float pxn = (pv4.x + (float)w) / gf;
            float pyn = (pv4.y + (float)h) / gf;
            float pwn = __expf(pv4.z) * ax * (1.0f / 416.0f);
            float phn = __expf(pv4.w) * ay * (1.0f / 416.0f);
            float pl = pxn - pwn * 0.5f, pr = pxn + pwn * 0.5f;
            float pt = pyn - phn * 0.5f, pb = pyn + phn * 0.5f;
            float p_area = pwn * phn;
            int listIdx = (lb == lbA) ? 0 : 1;
            int cntL = scnt[listIdx];
            const float* bx = sbox[listIdx];
            float maxiou = 0.0f;
            #pragma unroll 4
            for (int k = 0; k < cntL; ++k) {
                float bxx = bx[k * 4 + 0], byy = bx[k * 4 + 1];
                float bww = bx[k * 4 + 2], bhh = bx[k * 4 + 3];
                float il = fmaxf(pl, bxx - bww * 0.5f);
                float ir = fminf(pr, bxx + bww * 0.5f);
                float it = fmaxf(pt, byy - bhh * 0.5f);
                float ib = fminf(pb, byy + bhh * 0.5f);
                float iw = fmaxf(ir - il, 0.0f);
                float ih = fmaxf(ib - it, 0.0f);
                float inter = iw * ih;
                float iou = __fdividef(inter, p_area + bww * bhh - inter);
                maxiou = fmaxf(maxiou, iou);
            }
            if (maxiou < 0.5f) acc += -__logf(1.0f - pc);
        }
    }

    acc *= (1.0f / 16.0f);   // mean over batch == sum/16

    for (int off = 32; off > 0; off >>= 1)
        acc += __shfl_down(acc, off, 64);
    __shared__ float s[4];
    if (lane == 0) s[wid] = acc;
    __syncthreads();
    if (tid == 0) {
        float bpart = s[0] + s[1] + s[2] + s[3];
        atomicAdd(accum, bpart);
        __threadfence();                     // accum add complete before ticket
        int prev = atomicAdd(done2, 1);
        if (prev == NBLK - 1)                // exactly one last block
            out[0] = atomicAdd(accum, 0.0f);
    }
}

extern "C" void kernel_launch(void* const* d_in, const int* in_sizes, int n_in,
                              void* d_out, int out_size, void* d_ws, size_t ws_size,
                              hipStream_t stream) {
    const float* p0 = (const float*)d_in[0];
    const float* t0 = (const float*)d_in[1];
    const float* p1 = (const float*)d_in[2];
    const float* t1 = (const float*)d_in[3];
    const float* p2 = (const float*)d_in[4];
    const float* t2 = (const float*)d_in[5];

    int*   counts = (int*)d_ws;
    int*   done   = (int*)((char*)d_ws + DONE_OFF);
    int*   done2  = (int*)((char*)d_ws + DONE2_OFF);
    float* accum  = (float*)((char*)d_ws + ACC_OFF);
    float* boxes  = (float*)((char*)d_ws + BOX_OFF);
    float* outp   = (float*)d_out;

    (void)hipMemsetAsync(d_ws, 0, 512, stream);   // counts+done+done2+accum

    yolo_fused<<<NBLK, 256, 0, stream>>>(p0, t0, p1, t1, p2, t2,
                                         counts, done, done2, accum,
                                         boxes, outp);
}

// Round 11
// 54.337 us; speedup vs baseline: 1.1303x; 1.1303x over previous
//
#include <hip/hip_runtime.h>

#define CCH  85
#define MAXB 32

typedef float v4f __attribute__((ext_vector_type(4), aligned(4)));

// anchors fixed by reference setup_inputs; l0->mask[6,7,8], l1->[3,4,5], l2->[0,1,2]
__device__ __forceinline__ float anc_x(int l, int a) {
    if (l == 0) return (a == 0) ? 116.f : (a == 1) ? 156.f : 373.f;
    if (l == 1) return (a == 0) ?  30.f : (a == 1) ?  62.f :  59.f;
    return          (a == 0) ?  10.f : (a == 1) ?  16.f :  33.f;
}
__device__ __forceinline__ float anc_y(int l, int a) {
    if (l == 0) return (a == 0) ?  90.f : (a == 1) ? 198.f : 326.f;
    if (l == 1) return (a == 0) ?  61.f : (a == 1) ?  45.f : 119.f;
    return          (a == 0) ?  13.f : (a == 1) ?  30.f :  23.f;
}

// ---------------------------------------------------------------------------
// One block per (layer,image) span; l=2 spans get 2 blocks (each redundantly
// scans the span's obj channel -> ZERO cross-block communication).
//   blocks 0..31 : l=2, image=bid>>1, half=bid&1 (dispatched first: critical path)
//   blocks 32..47: l=1, image=bid-32
//   blocks 48..63: l=0, image=bid-48
// Per block: issue all gathers up front (one latency/fill phase), build box
// list in LDS, wave-coop obj-row loss (primary half only), conf-neg from regs.
// Ref's top_k(32)+(vals>0) mask == set of obj>0 boxes (<=20/image < 32);
// set-max IoU is order-independent -> append order irrelevant.
// ---------------------------------------------------------------------------
__global__ void __launch_bounds__(1024) yolo_span(
        const float* __restrict__ p0, const float* __restrict__ t0,
        const float* __restrict__ p1, const float* __restrict__ t1,
        const float* __restrict__ p2, const float* __restrict__ t2,
        float* __restrict__ out) {
    int bid = blockIdx.x;
    int tid = threadIdx.x;

    int l, b, half, g;
    if (bid < 32)      { l = 2; b = bid >> 1;  half = bid & 1; g = 52; }
    else if (bid < 48) { l = 1; b = bid - 32;  half = 0;       g = 26; }
    else               { l = 0; b = bid - 48;  half = 0;       g = 13; }
    const float* P = (l == 0) ? p0 : (l == 1) ? p1 : p2;
    const float* T = (l == 0) ? t0 : (l == 1) ? t1 : t2;
    int cpi = g * g * 3;                        // 8112 / 2028 / 507
    size_t sbase = (size_t)b * cpi * CCH;       // float offset of span start

    int nscan = (cpi + 1023) >> 10;             // 8 / 2 / 1
    int kbase = (l == 2) ? (half << 2) : 0;     // conf k-range start
    int nconf = (l == 2) ? 4 : nscan;           // 4 / 2 / 1

    // ---- issue ALL gathers up front: scan obj (<=8) + own pred (<=4x5) ----
    float ov[8];
    #pragma unroll
    for (int k = 0; k < 8; ++k) {
        int cc = (k << 10) + tid;
        ov[k] = 0.0f;
        if (k < nscan && cc < cpi)
            ov[k] = T[sbase + (size_t)cc * CCH + 4];
    }
    v4f  pv4a[4];
    float pca[4];
    #pragma unroll
    for (int kk = 0; kk < 4; ++kk) {
        int cc = ((kbase + kk) << 10) + tid;
        pv4a[kk] = (v4f){0.5f, 0.5f, 0.0f, 0.0f};
        pca[kk]  = 0.5f;
        if (kk < nconf && cc < cpi) {
            const float* pp = P + sbase + (size_t)cc * CCH;
            pv4a[kk] = *(const v4f*)pp;   // pred ch0..3 (dword-aligned)
            pca[kk]  = pp[4];
        }
    }

    // ---- build box list in LDS ----
    __shared__ int scnt;
    __shared__ float4 sbox[MAXB];
    __shared__ int scell[MAXB];
    if (tid == 0) scnt = 0;
    __syncthreads();

    #pragma unroll
    for (int k = 0; k < 8; ++k) {
        int cc = (k << 10) + tid;
        if (k < nscan && cc < cpi && ov[k] > 0.0f) {
            int pos = atomicAdd(&scnt, 1);
            if (pos < MAXB) {
                const float* tb = T + sbase + (size_t)cc * CCH;
                sbox[pos]  = make_float4(tb[0], tb[1], tb[2], tb[3]);
                scell[pos] = cc;
            }
        }
    }
    __syncthreads();
    int n = scnt < MAXB ? scnt : MAXB;

    float acc = 0.0f;
    int lane = tid & 63, wid = tid >> 6;

    // ---- obj-row loss (xy/wh/cls + conf-pos), primary block only ----
    if (half == 0) {
        for (int k = wid; k < n; k += 16) {
            int sc = scell[k];
            int a2 = sc % 3, w2 = (sc / 3) % g, h2 = sc / (3 * g);
            size_t base2 = sbase + (size_t)sc * CCH;
            float pv = P[base2 + lane];
            float tv = T[base2 + lane];
            bool has2 = lane < (CCH - 64);           // lanes 0..20 -> ch 64..84
            float pvB = 1.0f, tvB = 1.0f;
            if (has2) { pvB = P[base2 + 64 + lane]; tvB = T[base2 + 64 + lane]; }

            float tx = __shfl(tv, 0, 64), ty = __shfl(tv, 1, 64);
            float tw = __shfl(tv, 2, 64), th = __shfl(tv, 3, 64);
            float qx = __shfl(pv, 0, 64), qy = __shfl(pv, 1, 64);
            float qw = __shfl(pv, 2, 64), qh = __shfl(pv, 3, 64);
            float qc = __shfl(pv, 4, 64);

            if (lane >= 5)   // cls ch 5..63
                acc += -(tv * __logf(pv) + (1.0f - tv) * __logf(1.0f - pv));
            if (has2)        // cls ch 64..84
                acc += -(tvB * __logf(pvB) + (1.0f - tvB) * __logf(1.0f - pvB));

            if (lane == 0) {
                float scale = 2.0f - tw * th;
                float gf = (float)g;
                float rtx = tx * gf - (float)w2;
                float rty = ty * gf - (float)h2;
                float ax = anc_x(l, a2), ay = anc_y(l, a2);
                float rtw = __logf(tw * 416.0f / ax);   // tw,th > 0 at obj cells
                float rth = __logf(th * 416.0f / ay);
                acc += (-(rtx * __logf(qx) + (1.0f - rtx) * __logf(1.0f - qx))) * scale;
                acc += (-(rty * __logf(qy) + (1.0f - rty) * __logf(1.0f - qy))) * scale;
                acc += 0.5f * (qw - rtw) * (qw - rtw) * scale;
                acc += 0.5f * (qh - rth) * (qh - rth) * scale;
                acc += -__logf(qc);                     // conf-pos (factor==1)
            }
        }
    }

    // ---- conf-neg for owned cells (pred in regs, boxes in LDS) ----
    #pragma unroll
    for (int kk = 0; kk < 4; ++kk) {
        int k = kbase + kk;
        int cc = (k << 10) + tid;
        if (kk < nconf && cc < cpi && !(ov[k] > 0.0f)) {
            int a = cc % 3, w = (cc / 3) % g, h = cc / (3 * g);
            float ax = anc_x(l, a), ay = anc_y(l, a);
            float gf = (float)g;
            v4f pv4 = pv4a[kk];
            float pxn = (pv4.x + (float)w) / gf;
            float pyn = (pv4.y + (float)h) / gf;
            float pwn = __expf(pv4.z) * ax * (1.0f / 416.0f);
            float phn = __expf(pv4.w) * ay * (1.0f / 416.0f);
            float pl = pxn - pwn * 0.5f, pr = pxn + pwn * 0.5f;
            float pt = pyn - phn * 0.5f, pb = pyn + phn * 0.5f;
            float p_area = pwn * phn;
            float maxiou = 0.0f;
            for (int kb = 0; kb < n; ++kb) {
                float4 tb = sbox[kb];
                float il = fmaxf(pl, tb.x - tb.z * 0.5f);
                float ir = fminf(pr, tb.x + tb.z * 0.5f);
                float it = fmaxf(pt, tb.y - tb.w * 0.5f);
                float ib = fminf(pb, tb.y + tb.w * 0.5f);
                float iw = fmaxf(ir - il, 0.0f);
                float ih = fmaxf(ib - it, 0.0f);
                float inter = iw * ih;
                float iou = __fdividef(inter, p_area + tb.z * tb.w - inter);
                maxiou = fmaxf(maxiou, iou);
            }
            if (maxiou < 0.5f) acc += -__logf(1.0f - pca[kk]);
        }
    }

    acc *= (1.0f / 16.0f);   // mean over batch == sum/16

    // 16-wave block reduce -> one atomicAdd
    for (int off = 32; off > 0; off >>= 1)
        acc += __shfl_down(acc, off, 64);
    __shared__ float s[16];
    if (lane == 0) s[wid] = acc;
    __syncthreads();
    if (tid == 0) {
        float t = 0.0f;
        #pragma unroll
        for (int k = 0; k < 16; ++k) t += s[k];
        atomicAdd(out, t);
    }
}

extern "C" void kernel_launch(void* const* d_in, const int* in_sizes, int n_in,
                              void* d_out, int out_size, void* d_ws, size_t ws_size,
                              hipStream_t stream) {
    const float* p0 = (const float*)d_in[0];
    const float* t0 = (const float*)d_in[1];
    const float* p1 = (const float*)d_in[2];
    const float* t1 = (const float*)d_in[3];
    const float* p2 = (const float*)d_in[4];
    const float* t2 = (const float*)d_in[5];
    float* outp = (float*)d_out;

    (void)hipMemsetAsync(d_out, 0, sizeof(float), stream);
    yolo_span<<<64, 1024, 0, stream>>>(p0, t0, p1, t1, p2, t2, outp);
}

// Round 12
// 30.146 us; speedup vs baseline: 2.0373x; 1.8024x over previous
//
#include <hip/hip_runtime.h>

#define CCH  85
#define N0   (16*13*13*3)   // 8112
#define N1   (16*26*26*3)   // 32448
#define N2   (16*52*52*3)   // 129792
#define NTOT (N0+N1+N2)     // 170352
#define NBLK ((NTOT + 255) / 256)   // 666
#define BPB  40   // max boxes per K1 block (block spans <=2 images, <=20 each)
#define MAXB 32   // max boxes per (layer,image)

// d_ws layout (bytes):
//   FLAGS_OFF = 0      : uchar[NTOT]       per-cell obj flag
//   CNT_OFF   = 170368 : int[NBLK]         per-K1-block private box count
//   TAGS_OFF  = 173056 : int[NBLK*BPB]     lb tag per private box
//   BOX_OFF   = 280064 : float4[NBLK*BPB]  private boxes
#define FLAGS_OFF 0
#define CNT_OFF   170368
#define TAGS_OFF  173056
#define BOX_OFF   280064

typedef float v4f __attribute__((ext_vector_type(4), aligned(4)));

__device__ __forceinline__ void decode(int i, int& l, int& li, int& g) {
    if (i < N0)           { l = 0; li = i;           g = 13; }
    else if (i < N0 + N1) { l = 1; li = i - N0;      g = 26; }
    else                  { l = 2; li = i - N0 - N1; g = 52; }
}

// anchors fixed by reference setup_inputs; l0->mask[6,7,8], l1->[3,4,5], l2->[0,1,2]
__device__ __forceinline__ float anc_x(int l, int a) {
    if (l == 0) return (a == 0) ? 116.f : (a == 1) ? 156.f : 373.f;
    if (l == 1) return (a == 0) ?  30.f : (a == 1) ?  62.f :  59.f;
    return          (a == 0) ?  10.f : (a == 1) ?  16.f :  33.f;
}
__device__ __forceinline__ float anc_y(int l, int a) {
    if (l == 0) return (a == 0) ?  90.f : (a == 1) ? 198.f : 326.f;
    if (l == 1) return (a == 0) ?  61.f : (a == 1) ?  45.f : 119.f;
    return          (a == 0) ?  13.f : (a == 1) ?  30.f :  23.f;
}

__device__ __forceinline__ int lb_of(int gi) {
    int ll, lli, gg;
    decode(gi, ll, lli, gg);
    return ll * 16 + lli / (gg * gg * 3);
}

// ---------------------------------------------------------------------------
// K1: LEAN full-grid scan. Per cell: read tgt[4], write flag byte; obj cells
// append (box,tag) to the block's PRIVATE list (LDS -> plain global stores,
// counts_priv[bid] rewritten every call -> no zeroing/memset needed).
// Ref's top_k(32)+(vals>0) mask == set of obj>0 boxes (<=20/image < 32);
// set-max IoU is order-independent -> collection order irrelevant.
// ---------------------------------------------------------------------------
__global__ void __launch_bounds__(256) k1_scan(
        const float* __restrict__ t0, const float* __restrict__ t1,
        const float* __restrict__ t2,
        unsigned char* __restrict__ flags,
        int* __restrict__ counts_priv, int* __restrict__ tags_priv,
        float4* __restrict__ boxes_priv, float* __restrict__ out) {
    int bid = blockIdx.x;
    int tid = threadIdx.x;
    int i = bid * 256 + tid;
    bool valid = i < NTOT;

    int l = 0, li = 0, g = 13;
    if (valid) decode(i, l, li, g);
    const float* T = (l == 0) ? t0 : (l == 1) ? t1 : t2;
    size_t base = (size_t)li * CCH;

    float obj = 0.0f;
    if (valid) obj = T[base + 4];
    if (valid) flags[i] = (obj > 0.0f) ? 1 : 0;

    __shared__ int cnt;
    __shared__ float4 lbox[BPB];
    __shared__ int llb[BPB];
    if (tid == 0) cnt = 0;
    __syncthreads();

    if (valid && obj > 0.0f) {
        int cpi = g * g * 3;
        int b = li / cpi;
        int pos = atomicAdd(&cnt, 1);
        if (pos < BPB) {
            v4f tb4 = *(const v4f*)(T + base);   // tgt ch0..3
            lbox[pos] = make_float4(tb4.x, tb4.y, tb4.z, tb4.w);
            llb[pos]  = l * 16 + b;
        }
    }
    __syncthreads();

    int n = cnt < BPB ? cnt : BPB;
    if (tid == 0) counts_priv[bid] = n;
    if (tid < n) {
        boxes_priv[bid * BPB + tid] = lbox[tid];
        tags_priv[bid * BPB + tid]  = llb[tid];
    }
    if (bid == 0 && tid == 0) out[0] = 0.0f;   // K2 adds after kernel boundary
}

// ---------------------------------------------------------------------------
// K2: conf loss for all cells + ballot-inline obj-row loss (~1 row per wave,
// overlapped with the IoU work of the other lanes' cells). Box lists for the
// block's <=2 (layer,image) spans rebuilt in LDS from the <=33 overlapping
// K1 private lists.
// ---------------------------------------------------------------------------
__global__ void __launch_bounds__(256) k2_loss(
        const float* __restrict__ p0, const float* __restrict__ t0,
        const float* __restrict__ p1, const float* __restrict__ t1,
        const float* __restrict__ p2, const float* __restrict__ t2,
        const unsigned char* __restrict__ flags,
        const int* __restrict__ counts_priv, const int* __restrict__ tags_priv,
        const float4* __restrict__ boxes_priv, float* __restrict__ out) {
    int bid = blockIdx.x;
    int tid = threadIdx.x;
    int i = bid * 256 + tid;
    bool valid = i < NTOT;

    int l = 0, li = 0, g = 13;
    if (valid) decode(i, l, li, g);
    const float* P = (l == 0) ? p0 : (l == 1) ? p1 : p2;
    const float* T = (l == 0) ? t0 : (l == 1) ? t1 : t2;
    size_t base = (size_t)li * CCH;

    // long-latency gathers first; they overlap the box-list rebuild
    v4f pv4 = {0.5f, 0.5f, 0.0f, 0.0f};
    float pc = 0.5f;
    int flag = 0;
    if (valid) {
        pv4 = *(const v4f*)(P + base);
        pc  = P[base + 4];
        flag = flags[i];
    }

    int cpi = g * g * 3;
    int b = li / cpi;
    int c = li % cpi;
    int a = c % 3;
    int w = (c / 3) % g;
    int h = c / (3 * g);
    int lb = l * 16 + b;

    int iLast = (bid * 256 + 255 < NTOT) ? bid * 256 + 255 : NTOT - 1;
    int lbA = lb_of(bid * 256);
    int lbB = lb_of(iLast);

    __shared__ float4 sbox[2][MAXB];
    __shared__ int scnt[2];
    if (tid < 2) scnt[tid] = 0;
    __syncthreads();

    auto gather = [&](int lbT, int listIdx, int tbase) {
        int lT = lbT >> 4, bT = lbT & 15;
        int Ls, cpiT;
        if (lT == 0)      { Ls = 0;       cpiT = 13 * 13 * 3; }
        else if (lT == 1) { Ls = N0;      cpiT = 26 * 26 * 3; }
        else              { Ls = N0 + N1; cpiT = 52 * 52 * 3; }
        int jstart = (Ls + bT * cpiT) >> 8;
        int jend   = (Ls + (bT + 1) * cpiT - 1) >> 8;
        int t = tid - tbase;
        if (t >= 0 && t <= jend - jstart) {
            int j = jstart + t;
            int cj = counts_priv[j];
            if (cj > BPB) cj = BPB;
            for (int k = 0; k < cj; ++k) {
                if (tags_priv[j * BPB + k] == lbT) {
                    int p = atomicAdd(&scnt[listIdx], 1);
                    if (p < MAXB) sbox[listIdx][p] = boxes_priv[j * BPB + k];
                }
            }
        }
    };
    gather(lbA, 0, 0);
    if (lbB != lbA) gather(lbB, 1, 128);
    __syncthreads();

    float acc = 0.0f;
    int lane = tid & 63, wid = tid >> 6;

    // conf loss per cell
    if (valid) {
        if (flag) {
            acc = -__logf(pc);                       // (obj+(1-obj)*ignore)==1
        } else {
            float ax = anc_x(l, a), ay = anc_y(l, a);
            float gf = (float)g;
            float pxn = (pv4.x + (float)w) / gf;
            float pyn = (pv4.y + (float)h) / gf;
            float pwn = __expf(pv4.z) * ax * (1.0f / 416.0f);
            float phn = __expf(pv4.w) * ay * (1.0f / 416.0f);
            float pl = pxn - pwn * 0.5f, pr = pxn + pwn * 0.5f;
            float pt = pyn - phn * 0.5f, pb = pyn + phn * 0.5f;
            float p_area = pwn * phn;
            int listIdx = (lb == lbA) ? 0 : 1;
            int cntL = scnt[listIdx];
            if (cntL > MAXB) cntL = MAXB;
            const float4* bx = sbox[listIdx];
            float maxiou = 0.0f;
            #pragma unroll 4
            for (int k = 0; k < cntL; ++k) {
                float4 tb = bx[k];
                float il = fmaxf(pl, tb.x - tb.z * 0.5f);
                float ir = fminf(pr, tb.x + tb.z * 0.5f);
                float it = fmaxf(pt, tb.y - tb.w * 0.5f);
                float ib = fminf(pb, tb.y + tb.w * 0.5f);
                float iw = fmaxf(ir - il, 0.0f);
                float ih = fmaxf(ib - it, 0.0f);
                float inter = iw * ih;
                float iou = __fdividef(inter, p_area + tb.z * tb.w - inter);
                maxiou = fmaxf(maxiou, iou);
            }
            if (maxiou < 0.5f) acc = -__logf(1.0f - pc);
        }
    }

    // ballot-inline obj-row loss: wave cooperates on each obj lane's row
    unsigned long long mask = __ballot(valid && flag);
    while (mask) {
        int src = __ffsll(mask) - 1;
        mask &= mask - 1;
        int l2  = __shfl(l,  src, 64);
        int li2 = __shfl(li, src, 64);
        const float *P2 = (l2 == 0) ? p0 : (l2 == 1) ? p1 : p2;
        const float *T2 = (l2 == 0) ? t0 : (l2 == 1) ? t1 : t2;
        int g2 = (l2 == 0) ? 13 : (l2 == 1) ? 26 : 52;
        int cpi2 = g2 * g2 * 3;
        int c2 = li2 % cpi2;
        int a2 = c2 % 3;
        int w2 = (c2 / 3) % g2;
        int h2 = c2 / (3 * g2);
        size_t base2 = (size_t)li2 * CCH;

        float pv = P2[base2 + lane];
        float tv = T2[base2 + lane];
        bool has2 = lane < (CCH - 64);               // lanes 0..20 -> ch 64..84
        float pvB = 1.0f, tvB = 1.0f;
        if (has2) { pvB = P2[base2 + 64 + lane]; tvB = T2[base2 + 64 + lane]; }

        float tx = __shfl(tv, 0, 64), ty = __shfl(tv, 1, 64);
        float tw = __shfl(tv, 2, 64), th = __shfl(tv, 3, 64);
        float qx = __shfl(pv, 0, 64), qy = __shfl(pv, 1, 64);
        float qw = __shfl(pv, 2, 64), qh = __shfl(pv, 3, 64);

        if (lane >= 5)   // cls ch 5..63
            acc += -(tv * __logf(pv) + (1.0f - tv) * __logf(1.0f - pv));
        if (has2)        // cls ch 64..84
            acc += -(tvB * __logf(pvB) + (1.0f - tvB) * __logf(1.0f - pvB));

        if (lane == 0) {
            float scale = 2.0f - tw * th;
            float gf = (float)g2;
            float rtx = tx * gf - (float)w2;
            float rty = ty * gf - (float)h2;
            float ax = anc_x(l2, a2), ay = anc_y(l2, a2);
            float rtw = __logf(tw * 416.0f / ax);    // tw,th > 0 at obj cells
            float rth = __logf(th * 416.0f / ay);
            acc += (-(rtx * __logf(qx) + (1.0f - rtx) * __logf(1.0f - qx))) * scale;
            acc += (-(rty * __logf(qy) + (1.0f - rty) * __logf(1.0f - qy))) * scale;
            acc += 0.5f * (qw - rtw) * (qw - rtw) * scale;
            acc += 0.5f * (qh - rth) * (qh - rth) * scale;
        }
    }

    acc *= (1.0f / 16.0f);   // mean over batch == sum/16

    for (int off = 32; off > 0; off >>= 1)
        acc += __shfl_down(acc, off, 64);
    __shared__ float s[4];
    if (lane == 0) s[wid] = acc;
    __syncthreads();
    if (tid == 0)
        atomicAdd(out, s[0] + s[1] + s[2] + s[3]);
}

extern "C" void kernel_launch(void* const* d_in, const int* in_sizes, int n_in,
                              void* d_out, int out_size, void* d_ws, size_t ws_size,
                              hipStream_t stream) {
    const float* p0 = (const float*)d_in[0];
    const float* t0 = (const float*)d_in[1];
    const float* p1 = (const float*)d_in[2];
    const float* t1 = (const float*)d_in[3];
    const float* p2 = (const float*)d_in[4];
    const float* t2 = (const float*)d_in[5];

    unsigned char* flags = (unsigned char*)d_ws;
    int*    counts_priv  = (int*)((char*)d_ws + CNT_OFF);
    int*    tags_priv    = (int*)((char*)d_ws + TAGS_OFF);
    float4* boxes_priv   = (float4*)((char*)d_ws + BOX_OFF);
    float*  outp         = (float*)d_out;

    k1_scan<<<NBLK, 256, 0, stream>>>(t0, t1, t2, flags,
                                      counts_priv, tags_priv, boxes_priv, outp);
    k2_loss<<<NBLK, 256, 0, stream>>>(p0, t0, p1, t1, p2, t2, flags,
                                      counts_priv, tags_priv, boxes_priv, outp);
}